// Round 5
// baseline (337.466 us; speedup 1.0000x reference)
//
#include <hip/hip_runtime.h>
#include <hip/hip_bf16.h>
#include <math.h>

#define BATH 512
#define NH 8
#define HS 128
#define EMB 1024
#define NE 64
#define ES 128

typedef __attribute__((ext_vector_type(8))) short short8;
typedef __attribute__((ext_vector_type(4))) float floatx4;

__device__ __forceinline__ unsigned short f2b(float f) {   // f32 -> bf16 RNE
    union { float f; unsigned int u; } v; v.f = f;
    unsigned int r = v.u + 0x7FFFu + ((v.u >> 16) & 1u);
    return (unsigned short)(r >> 16);
}
__device__ __forceinline__ float b2f(unsigned short u) {   // bf16 -> f32 exact
    union { unsigned int u; float f; } v; v.u = ((unsigned int)u) << 16;
    return v.f;
}

// ---------------- convert w_mh, w_mg to bf16 (1M elems each) -------------------------
__global__ __launch_bounds__(256) void convert_w(const float* __restrict__ w_mh,
                                                 const float* __restrict__ w_mg,
                                                 unsigned short* __restrict__ w_mhb,
                                                 unsigned short* __restrict__ w_mgb)
{
    const int gid = blockIdx.x * 256 + threadIdx.x;       // 0..262143
    const int i8 = gid * 8;
    const float* src; unsigned short* dst; int off;
    if (i8 < (1 << 20)) { src = w_mh; dst = w_mhb; off = i8; }
    else                { src = w_mg; dst = w_mgb; off = i8 - (1 << 20); }
    const float4 a = *(const float4*)(src + off);
    const float4 b = *(const float4*)(src + off + 4);
    short8 p;
    p[0]=(short)f2b(a.x); p[1]=(short)f2b(a.y); p[2]=(short)f2b(a.z); p[3]=(short)f2b(a.w);
    p[4]=(short)f2b(b.x); p[5]=(short)f2b(b.y); p[6]=(short)f2b(b.z); p[7]=(short)f2b(b.w);
    *(short8*)(dst + off) = p;
}

// ---------------- Rt[h][e][d] = sum_hs w_mh[h*128+hs][d] * router[h][hs][e] ----------
__global__ __launch_bounds__(256) void rcomp(const float* __restrict__ w_mh,
                                             const float* __restrict__ router,
                                             float* __restrict__ Rt)
{
    const int h = blockIdx.x;              // 8
    const int d0 = blockIdx.y * 64;        // 16 tiles
    const int t = threadIdx.x;
    __shared__ __align__(16) float Ws[128][64];
    __shared__ __align__(16) float Rs[128][64];
#pragma unroll
    for (int i = 0; i < 8; ++i) {
        const int slot = t + i * 256;      // 2048
        const int hs = slot >> 4, c = slot & 15;
        *(float4*)&Ws[hs][c*4] = *(const float4*)(w_mh + (size_t)(h*128 + hs)*EMB + d0 + c*4);
        *(float4*)&Rs[hs][c*4] = *(const float4*)(router + (size_t)(h*128 + hs)*NE + c*4);
    }
    __syncthreads();
    const int e = t & 63, dg = t >> 6;
    float acc[16] = {};
    for (int hs = 0; hs < 128; ++hs) {
        const float rv = Rs[hs][e];
#pragma unroll
        for (int i = 0; i < 16; ++i) acc[i] += Ws[hs][dg*16 + i] * rv;
    }
    float* dst = Rt + (size_t)(h*64 + e)*EMB + d0 + dg*16;
#pragma unroll
    for (int i = 0; i < 16; ++i) dst[i] = acc[i];
}

// ---------------- router: f32 scores from x . Rt, biased top-2, gates, counts --------
__global__ __launch_bounds__(64) void router_topk2(
    const float* __restrict__ x, const float* __restrict__ Rt,
    const float* __restrict__ bias, int* __restrict__ idx,
    float* __restrict__ gate, int* __restrict__ counts)
{
    const int blk = blockIdx.x;            // h*512 + b
    const int h = blk >> 9;
    const int b = blk & (BATH - 1);
    const int e = threadIdx.x;             // 0..63
    const float4* xp = (const float4*)(x + (size_t)b * EMB);
    const float4* rp = (const float4*)(Rt + (size_t)(h*64 + e) * EMB);
    float4 a4 = {0.f, 0.f, 0.f, 0.f};
#pragma unroll 8
    for (int j = 0; j < 256; ++j) {
        const float4 xv = xp[j];
        const float4 rv = rp[j];
        a4.x += xv.x * rv.x; a4.y += xv.y * rv.y;
        a4.z += xv.z * rv.z; a4.w += xv.w * rv.w;
    }
    const float s = (a4.x + a4.y) + (a4.z + a4.w);
    const float biased = s + bias[h * NE + e];

    float v = biased; int vi = e;
#pragma unroll
    for (int off = 32; off > 0; off >>= 1) {
        float v2 = __shfl_xor(v, off);
        int   i2 = __shfl_xor(vi, off);
        if (v2 > v || (v2 == v && i2 < vi)) { v = v2; vi = i2; }
    }
    const int e1 = vi;
    float w = (e == e1) ? -3.4e38f : biased; int wi = e;
#pragma unroll
    for (int off = 32; off > 0; off >>= 1) {
        float v2 = __shfl_xor(w, off);
        int   i2 = __shfl_xor(wi, off);
        if (v2 > w || (v2 == w && i2 < wi)) { w = v2; wi = i2; }
    }
    const int e2 = wi;
    const float raw1 = __shfl(s, e1);
    const float raw2 = __shfl(s, e2);
    if (e == 0) {
        const float g1 = 1.f / (1.f + __expf(raw2 - raw1));
        idx[blk * 2 + 0]  = e1;
        idx[blk * 2 + 1]  = e2;
        gate[blk * 2 + 0] = g1;
        gate[blk * 2 + 1] = 1.f - g1;
        atomicAdd(&counts[h * NE + e1], 1);
        atomicAdd(&counts[h * NE + e2], 1);
    }
}

// ---------------- exclusive prefix over 512 expert counts; zero cursors --------------
__global__ __launch_bounds__(512) void scan_offsets(const int* __restrict__ counts,
                                                    int* __restrict__ offs,
                                                    int* __restrict__ cursor)
{
    __shared__ int tmp[512];
    const int t = threadIdx.x;
    const int c = counts[t];
    tmp[t] = c;
    __syncthreads();
    for (int off = 1; off < 512; off <<= 1) {
        int add = (t >= off) ? tmp[t - off] : 0;
        __syncthreads();
        tmp[t] += add;
        __syncthreads();
    }
    offs[t]   = tmp[t] - c;
    cursor[t] = 0;
}

// ---------------- scatter selection records into per-expert contiguous lists ---------
__global__ __launch_bounds__(256) void scatter_tokens(const int* __restrict__ idx,
                                                      const int* __restrict__ offs,
                                                      int* __restrict__ cursor,
                                                      int* __restrict__ list)
{
    const int g = blockIdx.x * blockDim.x + threadIdx.x;   // h*BATH + b
    if (g >= NH * BATH) return;
    const int h = g >> 9;
#pragma unroll
    for (int k = 0; k < 2; ++k) {
        const int e = idx[g * 2 + k];
        const int p = atomicAdd(&cursor[h * NE + e], 1);
        list[offs[h * NE + e] + p] = ((g & (BATH - 1)) << 1) | k;
    }
}

// ---------------- MFMA GEMM: C[M,N] f32 = A[M,K] f32 x B[N,K] bf16 (B^T layout) ------
// 64x64 tile, 4 waves of 32x32, 16x16x32 bf16 MFMA, A converted to bf16 in staging.
__global__ __launch_bounds__(256) void gemm_a32b16(
    const float* __restrict__ A, const unsigned short* __restrict__ B,
    float* __restrict__ C, int M, int N, int K)
{
    const int bm = blockIdx.y * 64;
    const int bn = blockIdx.x * 64;
    const int t = threadIdx.x;
    const int wid = t >> 6, l = t & 63;
    const int wm = (wid >> 1) * 32, wn = (wid & 1) * 32;
    const int lq = l >> 4, lr = l & 15;

    __shared__ __align__(16) unsigned short Al[64 * 32];
    __shared__ __align__(16) unsigned short Bl[64 * 32];

    const int srow = t >> 2, sg = t & 3;                 // staging: row, 16B-granule
    const float* Ap = A + (size_t)(bm + srow) * K + sg * 8;
    const unsigned short* Bp = B + (size_t)(bn + srow) * K + sg * 8;
    const int swz = (sg ^ ((srow >> 1) & 3)) * 8;        // XOR-swizzled granule slot

    const floatx4 z = {0.f, 0.f, 0.f, 0.f};
    floatx4 acc[2][2] = {{z, z}, {z, z}};

    float4 va0 = *(const float4*)(Ap);
    float4 va1 = *(const float4*)(Ap + 4);
    short8 vb  = *(const short8*)(Bp);

    const int nks = K >> 5;
    for (int ks = 0; ks < nks; ++ks) {
        short8 pa;
        pa[0]=(short)f2b(va0.x); pa[1]=(short)f2b(va0.y);
        pa[2]=(short)f2b(va0.z); pa[3]=(short)f2b(va0.w);
        pa[4]=(short)f2b(va1.x); pa[5]=(short)f2b(va1.y);
        pa[6]=(short)f2b(va1.z); pa[7]=(short)f2b(va1.w);
        *(short8*)&Al[srow * 32 + swz] = pa;
        *(short8*)&Bl[srow * 32 + swz] = vb;
        __syncthreads();
        if (ks + 1 < nks) {                               // prefetch next K-step
            va0 = *(const float4*)(Ap + (ks + 1) * 32);
            va1 = *(const float4*)(Ap + (ks + 1) * 32 + 4);
            vb  = *(const short8*)(Bp + (size_t)(ks + 1) * 32);
        }
        short8 af[2], bf[2];
#pragma unroll
        for (int i = 0; i < 2; ++i) {
            const int row = wm + i * 16 + lr;
            af[i] = *(const short8*)&Al[row * 32 + ((lq ^ ((row >> 1) & 3)) * 8)];
        }
#pragma unroll
        for (int j = 0; j < 2; ++j) {
            const int row = wn + j * 16 + lr;
            bf[j] = *(const short8*)&Bl[row * 32 + ((lq ^ ((row >> 1) & 3)) * 8)];
        }
#pragma unroll
        for (int i = 0; i < 2; ++i)
#pragma unroll
            for (int j = 0; j < 2; ++j)
                acc[i][j] = __builtin_amdgcn_mfma_f32_16x16x32_bf16(af[i], bf[j], acc[i][j], 0, 0, 0);
        __syncthreads();
    }
    // C/D layout: col = lane&15, row = (lane>>4)*4 + reg   [m89-verified]
#pragma unroll
    for (int i = 0; i < 2; ++i)
#pragma unroll
        for (int j = 0; j < 2; ++j)
#pragma unroll
            for (int r = 0; r < 4; ++r)
                C[(size_t)(bm + wm + i*16 + lq*4 + r) * N + bn + wn + j*16 + lr] = acc[i][j][r];
}

// ---------------- expert-major attention: block per (h,e), K once in LDS bf16 --------
__global__ __launch_bounds__(256) void expert_attn3(
    const float* __restrict__ q2, const float* __restrict__ k_ffwd,
    const float* __restrict__ v_ffwd, const float* __restrict__ gate,
    const int* __restrict__ list, const int* __restrict__ counts,
    const int* __restrict__ offs, float* __restrict__ agg2)
{
    const int he = blockIdx.x;
    const int n = counts[he];
    if (n == 0) return;
    const int h = he >> 6;
    const int base = offs[he];
    const int t = threadIdx.x;
    const int half = t >> 7;               // which chunk of the pair
    const int lane = t & 127;              // slot (phase A) / dim (phase B)

    __shared__ __align__(16) unsigned short Ks[128 * 128];  // swizzled bf16, 32KB
    __shared__ __align__(16) float qs[2][16][128];          // 16KB
    __shared__ __align__(16) float ps[2][16][128];          // 16KB
    __shared__ int tok[2][16];

    // stage K once: 128 rows x 16 granules (16B = 8 bf16), XOR-swizzle granule idx
    const float* Kg = k_ffwd + (size_t)he * (ES * HS);
#pragma unroll
    for (int i = 0; i < 8; ++i) {
        const int idx = t + i * 256;
        const int row = idx >> 4, g = idx & 15;
        const float4 va = *(const float4*)(Kg + row * 128 + g * 8);
        const float4 vb = *(const float4*)(Kg + row * 128 + g * 8 + 4);
        short8 p;
        p[0]=(short)f2b(va.x); p[1]=(short)f2b(va.y);
        p[2]=(short)f2b(va.z); p[3]=(short)f2b(va.w);
        p[4]=(short)f2b(vb.x); p[5]=(short)f2b(vb.y);
        p[6]=(short)f2b(vb.z); p[7]=(short)f2b(vb.w);
        *(short8*)&Ks[row * 128 + ((g ^ (row & 7)) * 8)] = p;
    }
    __syncthreads();

    const float* Vp = v_ffwd + (size_t)he * (ES * HS);
    const int npair = (n + 31) >> 5;

    for (int p = 0; p < npair; ++p) {
        const int c0 = (p * 2 + half) * 16;
        const int cnt = min(16, n - c0);           // <= 0 for idle tail half
        if (lane < 16) tok[half][lane] = (lane < cnt && lane >= 0) ? list[base + c0 + lane] : 0;
        __syncthreads();
        if (cnt > 0) {
#pragma unroll
            for (int i = 0; i < 16; ++i) {
                const int bb = tok[half][i] >> 1;
                qs[half][i][lane] = (i < cnt) ? q2[(size_t)bb * EMB + h * HS + lane] : 0.f;
            }
        }
        __syncthreads();
        if (cnt > 0) {                              // phase A: logits for slot=lane
            const int s = lane;
            float lg[16] = {};
#pragma unroll
            for (int j0 = 0; j0 < 4; ++j0) {
                float kv[32];
#pragma unroll
                for (int gg = 0; gg < 4; ++gg) {
                    const int gi = j0 * 4 + gg;
                    const short8 kr = *(const short8*)&Ks[s * 128 + ((gi ^ (s & 7)) * 8)];
#pragma unroll
                    for (int u = 0; u < 8; ++u) kv[gg * 8 + u] = b2f((unsigned short)kr[u]);
                }
#pragma unroll
                for (int i = 0; i < 16; ++i) {
                    float a = 0.f;
#pragma unroll
                    for (int j4 = 0; j4 < 8; ++j4) {
                        const float4 qv = *(const float4*)&qs[half][i][j0 * 32 + j4 * 4];
                        a += kv[j4*4+0]*qv.x + kv[j4*4+1]*qv.y + kv[j4*4+2]*qv.z + kv[j4*4+3]*qv.w;
                    }
                    lg[i] += a;
                }
            }
#pragma unroll
            for (int i = 0; i < 16; ++i) ps[half][i][s] = __expf(lg[i]);
        }
        __syncthreads();
        if (cnt > 0) {                              // phase B: O[i][d=lane], fold vsum
            const int d = lane;
            float oacc[16] = {};
            float vs = 0.f;
            for (int s0 = 0; s0 < 128; s0 += 8) {
                float vv[8];
#pragma unroll
                for (int u = 0; u < 8; ++u) vv[u] = Vp[(size_t)(s0 + u) * HS + d];
#pragma unroll
                for (int u = 0; u < 8; ++u) vs += vv[u];
#pragma unroll
                for (int i = 0; i < 16; ++i) {
                    const float4 p0 = *(const float4*)&ps[half][i][s0];
                    const float4 p1 = *(const float4*)&ps[half][i][s0 + 4];
                    oacc[i] += p0.x*vv[0] + p0.y*vv[1] + p0.z*vv[2] + p0.w*vv[3]
                             + p1.x*vv[4] + p1.y*vv[5] + p1.z*vv[6] + p1.w*vv[7];
                }
            }
#pragma unroll
            for (int i = 0; i < 16; ++i) {
                if (i < cnt) {
                    const int bb = tok[half][i] >> 1;
                    const int kk = tok[half][i] & 1;
                    const float g = gate[(((h << 9) | bb) << 1) + kk];
                    atomicAdd(&agg2[(size_t)bb * EMB + h * HS + d], g * (oacc[i] - vs));
                }
            }
        }
        __syncthreads();
    }
}

extern "C" void kernel_launch(void* const* d_in, const int* in_sizes, int n_in,
                              void* d_out, int out_size, void* d_ws, size_t ws_size,
                              hipStream_t stream)
{
    const float* x      = (const float*)d_in[0];
    const float* w_mh   = (const float*)d_in[1];
    const float* w_mg   = (const float*)d_in[2];
    const float* router = (const float*)d_in[3];
    const float* k_ffwd = (const float*)d_in[4];
    const float* v_ffwd = (const float*)d_in[5];
    const float* bias   = (const float*)d_in[6];
    float* out = (float*)d_out;

    char* ws = (char*)d_ws;
    float*          q2     = (float*)(ws);                        // 2MB  [512][1024] f32
    float*          agg2   = (float*)(ws + (2u << 20));           // 2MB
    unsigned short* w_mhb  = (unsigned short*)(ws + (4u << 20));  // 2MB bf16 [1024][1024]
    unsigned short* w_mgb  = (unsigned short*)(ws + (6u << 20));  // 2MB
    float*          Rt     = (float*)(ws + (8u << 20));           // 2MB  [8][64][1024] f32
    float*          gate   = (float*)(ws + (10u << 20));          // 32KB
    int*            idx    = (int*)  (ws + (10u << 20) + 32768);  // 32KB
    int*            counts = (int*)  (ws + (10u << 20) + 65536);  // 2KB
    int*            offs   = (int*)  (ws + (10u << 20) + 67584);  // 2KB
    int*            cursor = (int*)  (ws + (10u << 20) + 69632);  // 2KB
    int*            list   = (int*)  (ws + (10u << 20) + 71680);  // 32KB

    hipMemsetAsync(agg2, 0, 2u << 20, stream);
    hipMemsetAsync(counts, 0, 2048, stream);

    convert_w<<<1024, 256, 0, stream>>>(w_mh, w_mg, w_mhb, w_mgb);
    rcomp<<<dim3(8, 16), 256, 0, stream>>>(w_mh, router, Rt);
    router_topk2<<<NH * BATH, 64, 0, stream>>>(x, Rt, bias, idx, gate, counts);
    scan_offsets<<<1, 512, 0, stream>>>(counts, offs, cursor);
    scatter_tokens<<<16, 256, 0, stream>>>(idx, offs, cursor, list);
    gemm_a32b16<<<dim3(16, 8), 256, 0, stream>>>(x, w_mhb, q2, BATH, EMB, EMB);
    expert_attn3<<<NH * NE, 256, 0, stream>>>(q2, k_ffwd, v_ffwd, gate, list,
                                              counts, offs, agg2);
    gemm_a32b16<<<dim3(16, 8), 256, 0, stream>>>(agg2, w_mgb, out, BATH, EMB, EMB);
}

// Round 6
// 252.729 us; speedup vs baseline: 1.3353x; 1.3353x over previous
//
#include <hip/hip_runtime.h>
#include <hip/hip_bf16.h>
#include <math.h>

#define BATH 512
#define NH 8
#define HS 128
#define EMB 1024
#define NE 64
#define ES 128

typedef __attribute__((ext_vector_type(8))) short short8;
typedef __attribute__((ext_vector_type(4))) float floatx4;

__device__ __forceinline__ unsigned short f2b(float f) {   // f32 -> bf16 RNE
    union { float f; unsigned int u; } v; v.f = f;
    unsigned int r = v.u + 0x7FFFu + ((v.u >> 16) & 1u);
    return (unsigned short)(r >> 16);
}
__device__ __forceinline__ float b2f(unsigned short u) {   // bf16 -> f32 exact
    union { unsigned int u; float f; } v; v.u = ((unsigned int)u) << 16;
    return v.f;
}

// ---------------- convert w_mh, w_mg to bf16 (1M elems each) -------------------------
__global__ __launch_bounds__(256) void convert_w(const float* __restrict__ w_mh,
                                                 const float* __restrict__ w_mg,
                                                 unsigned short* __restrict__ w_mhb,
                                                 unsigned short* __restrict__ w_mgb)
{
    const int gid = blockIdx.x * 256 + threadIdx.x;       // 0..262143
    const int i8 = gid * 8;
    const float* src; unsigned short* dst; int off;
    if (i8 < (1 << 20)) { src = w_mh; dst = w_mhb; off = i8; }
    else                { src = w_mg; dst = w_mgb; off = i8 - (1 << 20); }
    const float4 a = *(const float4*)(src + off);
    const float4 b = *(const float4*)(src + off + 4);
    short8 p;
    p[0]=(short)f2b(a.x); p[1]=(short)f2b(a.y); p[2]=(short)f2b(a.z); p[3]=(short)f2b(a.w);
    p[4]=(short)f2b(b.x); p[5]=(short)f2b(b.y); p[6]=(short)f2b(b.z); p[7]=(short)f2b(b.w);
    *(short8*)(dst + off) = p;
}

// ------- Rt[h][e][d] = sum_hs w_mh[h*128+hs][d] * router[h][hs][e], emit bf16 hi/lo --
__global__ __launch_bounds__(256) void rcomp2(const float* __restrict__ w_mh,
                                              const float* __restrict__ router,
                                              unsigned short* __restrict__ RtHi,
                                              unsigned short* __restrict__ RtLo)
{
    const int h = blockIdx.x;              // 8
    const int d0 = blockIdx.y * 64;        // 16 tiles
    const int t = threadIdx.x;
    __shared__ __align__(16) float Ws[128][64];
    __shared__ __align__(16) float Rs[128][64];
#pragma unroll
    for (int i = 0; i < 8; ++i) {
        const int slot = t + i * 256;      // 2048
        const int hs = slot >> 4, c = slot & 15;
        *(float4*)&Ws[hs][c*4] = *(const float4*)(w_mh + (size_t)(h*128 + hs)*EMB + d0 + c*4);
        *(float4*)&Rs[hs][c*4] = *(const float4*)(router + (size_t)(h*128 + hs)*NE + c*4);
    }
    __syncthreads();
    const int e = t & 63, dg = t >> 6;
    float acc[16] = {};
    for (int hs = 0; hs < 128; ++hs) {
        const float rv = Rs[hs][e];
#pragma unroll
        for (int i = 0; i < 16; ++i) acc[i] += Ws[hs][dg*16 + i] * rv;
    }
    short8 hi0, hi1, lo0, lo1;
#pragma unroll
    for (int i = 0; i < 8; ++i) {
        unsigned short h0 = f2b(acc[i]);
        hi0[i] = (short)h0;
        lo0[i] = (short)f2b(acc[i] - b2f(h0));
        unsigned short h1 = f2b(acc[8 + i]);
        hi1[i] = (short)h1;
        lo1[i] = (short)f2b(acc[8 + i] - b2f(h1));
    }
    const size_t base = (size_t)(h*64 + e) * EMB + d0 + dg*16;
    *(short8*)(RtHi + base)     = hi0;
    *(short8*)(RtHi + base + 8) = hi1;
    *(short8*)(RtLo + base)     = lo0;
    *(short8*)(RtLo + base + 8) = lo1;
}

// ------- scores[b][he] = x[b] . Rt[he], split-bf16 3-pass MFMA (f32-accurate) --------
// M=512, N=512, K=1024; 64x64 tile, 4 waves of 32x32.
__global__ __launch_bounds__(256) void score_gemm(
    const float* __restrict__ A, const unsigned short* __restrict__ Bh,
    const unsigned short* __restrict__ Bl, float* __restrict__ C)
{
    const int K = 1024, N = 512;
    const int bm = blockIdx.y * 64;
    const int bn = blockIdx.x * 64;
    const int t = threadIdx.x;
    const int wid = t >> 6, l = t & 63;
    const int wm = (wid >> 1) * 32, wn = (wid & 1) * 32;
    const int lq = l >> 4, lr = l & 15;

    __shared__ __align__(16) unsigned short Ah[64 * 32];
    __shared__ __align__(16) unsigned short Al[64 * 32];
    __shared__ __align__(16) unsigned short Bhh[64 * 32];
    __shared__ __align__(16) unsigned short Bll[64 * 32];

    const int srow = t >> 2, sg = t & 3;
    const float* Ap = A + (size_t)(bm + srow) * K + sg * 8;
    const unsigned short* Bhp = Bh + (size_t)(bn + srow) * K + sg * 8;
    const unsigned short* Blp = Bl + (size_t)(bn + srow) * K + sg * 8;
    const int swz = (sg ^ ((srow >> 1) & 3)) * 8;

    const floatx4 z = {0.f, 0.f, 0.f, 0.f};
    floatx4 acc[2][2] = {{z, z}, {z, z}};

    float4 va0 = *(const float4*)(Ap);
    float4 va1 = *(const float4*)(Ap + 4);
    short8 vbh = *(const short8*)(Bhp);
    short8 vbl = *(const short8*)(Blp);

    const int nks = K >> 5;
    for (int ks = 0; ks < nks; ++ks) {
        short8 pah, pal;
        const float av[8] = {va0.x, va0.y, va0.z, va0.w, va1.x, va1.y, va1.z, va1.w};
#pragma unroll
        for (int u = 0; u < 8; ++u) {
            unsigned short hh = f2b(av[u]);
            pah[u] = (short)hh;
            pal[u] = (short)f2b(av[u] - b2f(hh));
        }
        *(short8*)&Ah[srow * 32 + swz]  = pah;
        *(short8*)&Al[srow * 32 + swz]  = pal;
        *(short8*)&Bhh[srow * 32 + swz] = vbh;
        *(short8*)&Bll[srow * 32 + swz] = vbl;
        __syncthreads();
        if (ks + 1 < nks) {
            va0 = *(const float4*)(Ap + (ks + 1) * 32);
            va1 = *(const float4*)(Ap + (ks + 1) * 32 + 4);
            vbh = *(const short8*)(Bhp + (size_t)(ks + 1) * 32);
            vbl = *(const short8*)(Blp + (size_t)(ks + 1) * 32);
        }
        short8 afh[2], afl[2], bfh[2], bfl[2];
#pragma unroll
        for (int i = 0; i < 2; ++i) {
            const int row = wm + i * 16 + lr;
            const int o = row * 32 + ((lq ^ ((row >> 1) & 3)) * 8);
            afh[i] = *(const short8*)&Ah[o];
            afl[i] = *(const short8*)&Al[o];
        }
#pragma unroll
        for (int j = 0; j < 2; ++j) {
            const int row = wn + j * 16 + lr;
            const int o = row * 32 + ((lq ^ ((row >> 1) & 3)) * 8);
            bfh[j] = *(const short8*)&Bhh[o];
            bfl[j] = *(const short8*)&Bll[o];
        }
#pragma unroll
        for (int i = 0; i < 2; ++i)
#pragma unroll
            for (int j = 0; j < 2; ++j) {
                floatx4 a = acc[i][j];
                a = __builtin_amdgcn_mfma_f32_16x16x32_bf16(afl[i], bfh[j], a, 0, 0, 0);
                a = __builtin_amdgcn_mfma_f32_16x16x32_bf16(afh[i], bfl[j], a, 0, 0, 0);
                a = __builtin_amdgcn_mfma_f32_16x16x32_bf16(afh[i], bfh[j], a, 0, 0, 0);
                acc[i][j] = a;
            }
        __syncthreads();
    }
#pragma unroll
    for (int i = 0; i < 2; ++i)
#pragma unroll
        for (int j = 0; j < 2; ++j)
#pragma unroll
            for (int r = 0; r < 4; ++r)
                C[(size_t)(bm + wm + i*16 + lq*4 + r) * N + bn + wn + j*16 + lr] = acc[i][j][r];
}

// ---------------- top-2 selection from precomputed scores (wave per (h,b)) -----------
__global__ __launch_bounds__(256) void topk_sel(
    const float* __restrict__ scores, const float* __restrict__ bias,
    int* __restrict__ idx, float* __restrict__ gate, int* __restrict__ counts)
{
    const int g = blockIdx.x * 4 + (threadIdx.x >> 6);    // (h*512+b), 0..4095
    const int h = g >> 9;
    const int b = g & (BATH - 1);
    const int e = threadIdx.x & 63;
    const float s = scores[(size_t)b * 512 + h * 64 + e]; // coalesced 256B row
    const float biased = s + bias[h * NE + e];

    float v = biased; int vi = e;
#pragma unroll
    for (int off = 32; off > 0; off >>= 1) {
        float v2 = __shfl_xor(v, off);
        int   i2 = __shfl_xor(vi, off);
        if (v2 > v || (v2 == v && i2 < vi)) { v = v2; vi = i2; }
    }
    const int e1 = vi;
    float w = (e == e1) ? -3.4e38f : biased; int wi = e;
#pragma unroll
    for (int off = 32; off > 0; off >>= 1) {
        float v2 = __shfl_xor(w, off);
        int   i2 = __shfl_xor(wi, off);
        if (v2 > w || (v2 == w && i2 < wi)) { w = v2; wi = i2; }
    }
    const int e2 = wi;
    const float raw1 = __shfl(s, e1);
    const float raw2 = __shfl(s, e2);
    if (e == 0) {
        const float g1 = 1.f / (1.f + __expf(raw2 - raw1));
        idx[g * 2 + 0]  = e1;
        idx[g * 2 + 1]  = e2;
        gate[g * 2 + 0] = g1;
        gate[g * 2 + 1] = 1.f - g1;
        atomicAdd(&counts[h * NE + e1], 1);
        atomicAdd(&counts[h * NE + e2], 1);
    }
}

// ---------------- exclusive prefix over 512 expert counts; zero cursors --------------
__global__ __launch_bounds__(512) void scan_offsets(const int* __restrict__ counts,
                                                    int* __restrict__ offs,
                                                    int* __restrict__ cursor)
{
    __shared__ int tmp[512];
    const int t = threadIdx.x;
    const int c = counts[t];
    tmp[t] = c;
    __syncthreads();
    for (int off = 1; off < 512; off <<= 1) {
        int add = (t >= off) ? tmp[t - off] : 0;
        __syncthreads();
        tmp[t] += add;
        __syncthreads();
    }
    offs[t]   = tmp[t] - c;
    cursor[t] = 0;
}

// ---------------- scatter selection records into per-expert contiguous lists ---------
__global__ __launch_bounds__(256) void scatter_tokens(const int* __restrict__ idx,
                                                      const int* __restrict__ offs,
                                                      int* __restrict__ cursor,
                                                      int* __restrict__ list)
{
    const int g = blockIdx.x * blockDim.x + threadIdx.x;   // h*BATH + b
    if (g >= NH * BATH) return;
    const int h = g >> 9;
#pragma unroll
    for (int k = 0; k < 2; ++k) {
        const int e = idx[g * 2 + k];
        const int p = atomicAdd(&cursor[h * NE + e], 1);
        list[offs[h * NE + e] + p] = ((g & (BATH - 1)) << 1) | k;
    }
}

// ---------------- MFMA GEMM: C[M,N] f32 = A[M,K] f32 x B[N,K] bf16 (B^T layout) ------
__global__ __launch_bounds__(256) void gemm_a32b16(
    const float* __restrict__ A, const unsigned short* __restrict__ B,
    float* __restrict__ C, int M, int N, int K)
{
    const int bm = blockIdx.y * 64;
    const int bn = blockIdx.x * 64;
    const int t = threadIdx.x;
    const int wid = t >> 6, l = t & 63;
    const int wm = (wid >> 1) * 32, wn = (wid & 1) * 32;
    const int lq = l >> 4, lr = l & 15;

    __shared__ __align__(16) unsigned short Al[64 * 32];
    __shared__ __align__(16) unsigned short Bl[64 * 32];

    const int srow = t >> 2, sg = t & 3;
    const float* Ap = A + (size_t)(bm + srow) * K + sg * 8;
    const unsigned short* Bp = B + (size_t)(bn + srow) * K + sg * 8;
    const int swz = (sg ^ ((srow >> 1) & 3)) * 8;

    const floatx4 z = {0.f, 0.f, 0.f, 0.f};
    floatx4 acc[2][2] = {{z, z}, {z, z}};

    float4 va0 = *(const float4*)(Ap);
    float4 va1 = *(const float4*)(Ap + 4);
    short8 vb  = *(const short8*)(Bp);

    const int nks = K >> 5;
    for (int ks = 0; ks < nks; ++ks) {
        short8 pa;
        pa[0]=(short)f2b(va0.x); pa[1]=(short)f2b(va0.y);
        pa[2]=(short)f2b(va0.z); pa[3]=(short)f2b(va0.w);
        pa[4]=(short)f2b(va1.x); pa[5]=(short)f2b(va1.y);
        pa[6]=(short)f2b(va1.z); pa[7]=(short)f2b(va1.w);
        *(short8*)&Al[srow * 32 + swz] = pa;
        *(short8*)&Bl[srow * 32 + swz] = vb;
        __syncthreads();
        if (ks + 1 < nks) {
            va0 = *(const float4*)(Ap + (ks + 1) * 32);
            va1 = *(const float4*)(Ap + (ks + 1) * 32 + 4);
            vb  = *(const short8*)(Bp + (size_t)(ks + 1) * 32);
        }
        short8 af[2], bf[2];
#pragma unroll
        for (int i = 0; i < 2; ++i) {
            const int row = wm + i * 16 + lr;
            af[i] = *(const short8*)&Al[row * 32 + ((lq ^ ((row >> 1) & 3)) * 8)];
        }
#pragma unroll
        for (int j = 0; j < 2; ++j) {
            const int row = wn + j * 16 + lr;
            bf[j] = *(const short8*)&Bl[row * 32 + ((lq ^ ((row >> 1) & 3)) * 8)];
        }
#pragma unroll
        for (int i = 0; i < 2; ++i)
#pragma unroll
            for (int j = 0; j < 2; ++j)
                acc[i][j] = __builtin_amdgcn_mfma_f32_16x16x32_bf16(af[i], bf[j], acc[i][j], 0, 0, 0);
        __syncthreads();
    }
#pragma unroll
    for (int i = 0; i < 2; ++i)
#pragma unroll
        for (int j = 0; j < 2; ++j)
#pragma unroll
            for (int r = 0; r < 4; ++r)
                C[(size_t)(bm + wm + i*16 + lq*4 + r) * N + bn + wn + j*16 + lr] = acc[i][j][r];
}

// ---------------- expert-major attention: block per (h,e), K once in LDS bf16 --------
__global__ __launch_bounds__(256) void expert_attn3(
    const float* __restrict__ q2, const float* __restrict__ k_ffwd,
    const float* __restrict__ v_ffwd, const float* __restrict__ gate,
    const int* __restrict__ list, const int* __restrict__ counts,
    const int* __restrict__ offs, float* __restrict__ agg2)
{
    const int he = blockIdx.x;
    const int n = counts[he];
    if (n == 0) return;
    const int h = he >> 6;
    const int base = offs[he];
    const int t = threadIdx.x;
    const int half = t >> 7;               // which chunk of the pair
    const int lane = t & 127;              // slot (phase A) / dim (phase B)

    __shared__ __align__(16) unsigned short Ks[128 * 128];  // swizzled bf16, 32KB
    __shared__ __align__(16) float qs[2][16][128];          // 16KB
    __shared__ __align__(16) float ps[2][16][128];          // 16KB
    __shared__ int tok[2][16];

    const float* Kg = k_ffwd + (size_t)he * (ES * HS);
#pragma unroll
    for (int i = 0; i < 8; ++i) {
        const int idx = t + i * 256;
        const int row = idx >> 4, g = idx & 15;
        const float4 va = *(const float4*)(Kg + row * 128 + g * 8);
        const float4 vb = *(const float4*)(Kg + row * 128 + g * 8 + 4);
        short8 p;
        p[0]=(short)f2b(va.x); p[1]=(short)f2b(va.y);
        p[2]=(short)f2b(va.z); p[3]=(short)f2b(va.w);
        p[4]=(short)f2b(vb.x); p[5]=(short)f2b(vb.y);
        p[6]=(short)f2b(vb.z); p[7]=(short)f2b(vb.w);
        *(short8*)&Ks[row * 128 + ((g ^ (row & 7)) * 8)] = p;
    }
    __syncthreads();

    const float* Vp = v_ffwd + (size_t)he * (ES * HS);
    const int npair = (n + 31) >> 5;

    for (int p = 0; p < npair; ++p) {
        const int c0 = (p * 2 + half) * 16;
        const int cnt = min(16, n - c0);
        if (lane < 16) tok[half][lane] = (lane < cnt) ? list[base + c0 + lane] : 0;
        __syncthreads();
        if (cnt > 0) {
#pragma unroll
            for (int i = 0; i < 16; ++i) {
                const int bb = tok[half][i] >> 1;
                qs[half][i][lane] = (i < cnt) ? q2[(size_t)bb * EMB + h * HS + lane] : 0.f;
            }
        }
        __syncthreads();
        if (cnt > 0) {                              // phase A: logits for slot=lane
            const int s = lane;
            float lg[16] = {};
#pragma unroll
            for (int g = 0; g < 16; ++g) {          // 16 granules of 8 k-dims
                const short8 kr = *(const short8*)&Ks[s * 128 + ((g ^ (s & 7)) * 8)];
                float kv[8];
#pragma unroll
                for (int u = 0; u < 8; ++u) kv[u] = b2f((unsigned short)kr[u]);
#pragma unroll
                for (int i = 0; i < 16; ++i) {
                    const float4 q0 = *(const float4*)&qs[half][i][g * 8];
                    const float4 q1 = *(const float4*)&qs[half][i][g * 8 + 4];
                    lg[i] += kv[0]*q0.x + kv[1]*q0.y + kv[2]*q0.z + kv[3]*q0.w
                           + kv[4]*q1.x + kv[5]*q1.y + kv[6]*q1.z + kv[7]*q1.w;
                }
            }
#pragma unroll
            for (int i = 0; i < 16; ++i) ps[half][i][s] = __expf(lg[i]);
        }
        __syncthreads();
        if (cnt > 0) {                              // phase B: O[i][d=lane], fold vsum
            const int d = lane;
            float oacc[16] = {};
            float vs = 0.f;
            for (int s0 = 0; s0 < 128; s0 += 8) {
                float vv[8];
#pragma unroll
                for (int u = 0; u < 8; ++u) vv[u] = Vp[(size_t)(s0 + u) * HS + d];
#pragma unroll
                for (int u = 0; u < 8; ++u) vs += vv[u];
#pragma unroll
                for (int i = 0; i < 16; ++i) {
                    const float4 p0 = *(const float4*)&ps[half][i][s0];
                    const float4 p1 = *(const float4*)&ps[half][i][s0 + 4];
                    oacc[i] += p0.x*vv[0] + p0.y*vv[1] + p0.z*vv[2] + p0.w*vv[3]
                             + p1.x*vv[4] + p1.y*vv[5] + p1.z*vv[6] + p1.w*vv[7];
                }
            }
#pragma unroll
            for (int i = 0; i < 16; ++i) {
                if (i < cnt) {
                    const int bb = tok[half][i] >> 1;
                    const int kk = tok[half][i] & 1;
                    const float g = gate[(((h << 9) | bb) << 1) + kk];
                    atomicAdd(&agg2[(size_t)bb * EMB + h * HS + d], g * (oacc[i] - vs));
                }
            }
        }
        __syncthreads();
    }
}

extern "C" void kernel_launch(void* const* d_in, const int* in_sizes, int n_in,
                              void* d_out, int out_size, void* d_ws, size_t ws_size,
                              hipStream_t stream)
{
    const float* x      = (const float*)d_in[0];
    const float* w_mh   = (const float*)d_in[1];
    const float* w_mg   = (const float*)d_in[2];
    const float* router = (const float*)d_in[3];
    const float* k_ffwd = (const float*)d_in[4];
    const float* v_ffwd = (const float*)d_in[5];
    const float* bias   = (const float*)d_in[6];
    float* out = (float*)d_out;

    char* ws = (char*)d_ws;
    float*          q2     = (float*)(ws);                        // 2MB [512][1024] f32
    float*          agg2   = (float*)(ws + (2u << 20));           // 2MB
    unsigned short* w_mhb  = (unsigned short*)(ws + (4u << 20));  // 2MB bf16
    unsigned short* w_mgb  = (unsigned short*)(ws + (6u << 20));  // 2MB bf16
    unsigned short* RtHi   = (unsigned short*)(ws + (8u << 20));  // 1MB bf16 [512][1024]
    unsigned short* RtLo   = (unsigned short*)(ws + (9u << 20));  // 1MB bf16
    float*          scores = (float*)(ws + (10u << 20));          // 1MB [512][512] f32
    float*          gate   = (float*)(ws + (11u << 20));          // 32KB
    int*            idx    = (int*)  (ws + (11u << 20) + 32768);  // 32KB
    int*            counts = (int*)  (ws + (11u << 20) + 65536);  // 2KB
    int*            offs   = (int*)  (ws + (11u << 20) + 67584);  // 2KB
    int*            cursor = (int*)  (ws + (11u << 20) + 69632);  // 2KB
    int*            list   = (int*)  (ws + (11u << 20) + 71680);  // 32KB

    hipMemsetAsync(agg2, 0, 2u << 20, stream);
    hipMemsetAsync(counts, 0, 2048, stream);

    convert_w<<<1024, 256, 0, stream>>>(w_mh, w_mg, w_mhb, w_mgb);
    rcomp2<<<dim3(8, 16), 256, 0, stream>>>(w_mh, router, RtHi, RtLo);
    score_gemm<<<dim3(8, 8), 256, 0, stream>>>(x, RtHi, RtLo, scores);
    topk_sel<<<1024, 256, 0, stream>>>(scores, bias, idx, gate, counts);
    scan_offsets<<<1, 512, 0, stream>>>(counts, offs, cursor);
    scatter_tokens<<<16, 256, 0, stream>>>(idx, offs, cursor, list);
    gemm_a32b16<<<dim3(16, 8), 256, 0, stream>>>(x, w_mhb, q2, BATH, EMB, EMB);
    expert_attn3<<<NH * NE, 256, 0, stream>>>(q2, k_ffwd, v_ffwd, gate, list,
                                              counts, offs, agg2);
    gemm_a32b16<<<dim3(16, 8), 256, 0, stream>>>(agg2, w_mgb, out, BATH, EMB, EMB);
}